// Round 4
// baseline (379.385 us; speedup 1.0000x reference)
//
#include <hip/hip_runtime.h>
#include <math.h>

#define HW 65536
#define BN 16

// ws layout (floats):
//   ws[0] : mask-loss sum,  ws[1] : skin-loss sum
//   per-b block of 9 at ws[2 + b*9]:
//     +0..2 : nocs msum,cnt,dsum  +3..5 : locmap  +6..8 : rotmap
//   per-(b,j) block of 7 at ws[38 + (b*16+j)*7]: S, Nloc0..2, Nrot0..2
// total = 38 + 64*7 = 486 floats

__device__ __forceinline__ float fsig(float x) {
    return __builtin_amdgcn_rcpf(1.0f + __expf(-x));
}
__device__ __forceinline__ float sq(float x) { return x * x; }

__device__ __forceinline__ float wred(float v) {
#pragma unroll
    for (int off = 32; off; off >>= 1) v += __shfl_xor(v, off, 64);
    return v;
}

// ---- Fused kernel: float2, double-buffered j-pipeline, reduced DS --------
// grid (128, 4) = 512 blocks x 256 thr -> 2 blocks/CU, 8 waves/CU
__global__ __launch_bounds__(256) void mvpm_fused(const float* __restrict__ outp,
                                                  const float* __restrict__ tarp,
                                                  float* __restrict__ ws) {
    const int b = blockIdx.y;
    const int t2 = blockIdx.x * 256 + threadIdx.x;      // float2 index
    const int C2 = HW / 2;                              // channel stride (float2)
    const float2* ob = (const float2*)(outp + (size_t)b * 134 * HW) + t2;
    const float2* tb = (const float2*)(tarp + (size_t)b * 101 * HW) + t2;
    const int lane = threadIdx.x & 63;
    const int wv = threadIdx.x >> 6;
    const int l7 = lane & 7;

    __shared__ float jacc[BN][7][4];    // per-j, per-component, per-wave
    __shared__ float red[11][4];

    // -- mask, mask-logit, nocs (8 loads) --
    const float2 m2 = tb[3 * C2];
    const float2 ml = ob[3 * C2];
    const float2 a0 = ob[0], a1 = ob[C2], a2 = ob[2 * C2];
    const float2 b0 = tb[0], b1 = tb[C2], b2 = tb[2 * C2];

    const float bce =
        (m2.x * fminf(ml.x, 0.0f) + (1.0f - m2.x) * fminf(-ml.x, 0.0f)
         - __logf(1.0f + __expf(-fabsf(ml.x)))) +
        (m2.y * fminf(ml.y, 0.0f) + (1.0f - m2.y) * fminf(-ml.y, 0.0f)
         - __logf(1.0f + __expf(-fabsf(ml.y))));

    const float dnx = sqrtf(sq(a0.x - b0.x) + sq(a1.x - b1.x) + sq(a2.x - b2.x));
    const float dny = sqrtf(sq(a0.y - b0.y) + sq(a1.y - b1.y) + sq(a2.y - b2.y));
    const bool sx = m2.x > 0.7f, sy = m2.y > 0.7f;
    const float mmx = m2.x * m2.x, mmy = m2.y * m2.y;

    // -- skin CE: 18-channel batch --
    float2 x[18];
#pragma unroll
    for (int k = 0; k < 18; ++k) x[k] = ob[(100 + k) * C2];
    const float2 labf = tb[100 * C2];
    float mxx = x[0].x, mxy = x[0].y;
#pragma unroll
    for (int k = 1; k < 18; ++k) { mxx = fmaxf(mxx, x[k].x); mxy = fmaxf(mxy, x[k].y); }
    float sex = 0.0f, sey = 0.0f;
#pragma unroll
    for (int k = 0; k < 18; ++k) { sex += __expf(x[k].x - mxx); sey += __expf(x[k].y - mxy); }
    int labx = (int)labf.x; labx = labx < 0 ? 0 : (labx > 17 ? 17 : labx);
    int laby = (int)labf.y; laby = laby < 0 ? 0 : (laby > 17 ? 17 : laby);
    float xlx = x[0].x, xly = x[0].y;
#pragma unroll
    for (int k = 1; k < 18; ++k) { xlx = (labx == k) ? x[k].x : xlx;
                                   xly = (laby == k) ? x[k].y : xly; }
    const float skin = (mxx + __logf(sex) - xlx) + (mxy + __logf(sey) - xly);

    // -- joint loop: 13 float2 loads / j, double-buffered, 21 DS / j --
    float dslx = 0.0f, dsly = 0.0f, dsrx = 0.0f, dsry = 0.0f;
    float rj[BN];

#define LOADJ(buf, j)                                                          \
    {                                                                          \
        const int cl = (4 + 3 * (j)) * C2, cr = (52 + 3 * (j)) * C2;           \
        buf[0] = ob[cl]; buf[1] = ob[cl + C2]; buf[2] = ob[cl + 2 * C2];       \
        buf[3] = tb[cl]; buf[4] = tb[cl + C2]; buf[5] = tb[cl + 2 * C2];       \
        buf[6] = ob[cr]; buf[7] = ob[cr + C2]; buf[8] = ob[cr + 2 * C2];       \
        buf[9] = tb[cr]; buf[10] = tb[cr + C2]; buf[11] = tb[cr + 2 * C2];     \
        buf[12] = ob[(118 + (j)) * C2];                                        \
    }

#define COMPUTEJ(buf, j)                                                       \
    {                                                                          \
        const float so0x = fsig(buf[0].x), so0y = fsig(buf[0].y);              \
        const float so1x = fsig(buf[1].x), so1y = fsig(buf[1].y);              \
        const float so2x = fsig(buf[2].x), so2y = fsig(buf[2].y);              \
        const float sp0x = fsig(buf[6].x), sp0y = fsig(buf[6].y);              \
        const float sp1x = fsig(buf[7].x), sp1y = fsig(buf[7].y);              \
        const float sp2x = fsig(buf[8].x), sp2y = fsig(buf[8].y);              \
        dslx += sq(so0x - fsig(buf[3].x)) + sq(so1x - fsig(buf[4].x))          \
              + sq(so2x - fsig(buf[5].x));                                     \
        dsly += sq(so0y - fsig(buf[3].y)) + sq(so1y - fsig(buf[4].y))          \
              + sq(so2y - fsig(buf[5].y));                                     \
        dsrx += sq(sp0x - fsig(buf[9].x)) + sq(sp1x - fsig(buf[10].x))         \
              + sq(sp2x - fsig(buf[11].x));                                    \
        dsry += sq(sp0y - fsig(buf[9].y)) + sq(sp1y - fsig(buf[10].y))         \
              + sq(sp2y - fsig(buf[11].y));                                    \
        const float ssx = fsig(buf[12].x), ssy = fsig(buf[12].y);              \
        const float wx = ssx * mmx, wy = ssy * mmy;                            \
        float u[7];                                                            \
        u[0] = ssx * m2.x + ssy * m2.y;                                        \
        u[1] = so0x * wx + so0y * wy;                                          \
        u[2] = so1x * wx + so1y * wy;                                          \
        u[3] = so2x * wx + so2y * wy;                                          \
        u[4] = sp0x * wx + sp0y * wy;                                          \
        u[5] = sp1x * wx + sp1y * wy;                                          \
        u[6] = sp2x * wx + sp2y * wy;                                          \
        _Pragma("unroll")                                                      \
        for (int off = 1; off <= 4; off <<= 1) {                               \
            _Pragma("unroll")                                                  \
            for (int i = 0; i < 7; ++i) u[i] += __shfl_xor(u[i], off, 64);     \
        }                                                                      \
        float r = u[0];                                                        \
        r = (l7 == 1) ? u[1] : r;                                              \
        r = (l7 == 2) ? u[2] : r;                                              \
        r = (l7 == 3) ? u[3] : r;                                              \
        r = (l7 == 4) ? u[4] : r;                                              \
        r = (l7 == 5) ? u[5] : r;                                              \
        r = (l7 == 6) ? u[6] : r;                                              \
        rj[j] = r;                                                             \
    }

    float2 A[13], B[13];
    LOADJ(A, 0);
#pragma unroll
    for (int jj = 0; jj < BN; jj += 2) {
        LOADJ(B, jj + 1);
        COMPUTEJ(A, jj);
        if (jj + 2 < BN) LOADJ(A, jj + 2);
        COMPUTEJ(B, jj + 1);
    }
#undef LOADJ
#undef COMPUTEJ

    // deferred cross-group tail: 3 shuffles per j, masked single LDS write
#pragma unroll
    for (int j = 0; j < BN; ++j) {
        float r = rj[j];
        r += __shfl_xor(r, 8, 64);
        r += __shfl_xor(r, 16, 64);
        r += __shfl_xor(r, 32, 64);
        if (lane < 7) jacc[j][lane][wv] = r;
    }

    const float dnlx = sqrtf(dslx), dnly = sqrtf(dsly);
    const float dnrx = sqrtf(dsrx), dnry = sqrtf(dsry);

    // -- 11 pixel-loss wave reductions, both pixels pre-summed --
    float v[11];
    v[0]  = bce;
    v[1]  = skin;
    v[2]  = (sx ? dnx : 0.0f) + (sy ? dny : 0.0f);
    v[3]  = ((sx && dnx != 0.0f) ? 1.0f : 0.0f) + ((sy && dny != 0.0f) ? 1.0f : 0.0f);
    v[4]  = dnx + dny;
    v[5]  = (sx ? dnlx : 0.0f) + (sy ? dnly : 0.0f);
    v[6]  = ((sx && dnlx != 0.0f) ? 1.0f : 0.0f) + ((sy && dnly != 0.0f) ? 1.0f : 0.0f);
    v[7]  = dnlx + dnly;
    v[8]  = (sx ? dnrx : 0.0f) + (sy ? dnry : 0.0f);
    v[9]  = ((sx && dnrx != 0.0f) ? 1.0f : 0.0f) + ((sy && dnry != 0.0f) ? 1.0f : 0.0f);
    v[10] = dnrx + dnry;

#pragma unroll
    for (int off = 32; off; off >>= 1) {
#pragma unroll
        for (int i = 0; i < 11; ++i) v[i] += __shfl_xor(v[i], off, 64);
    }
    if (lane == 0) {
#pragma unroll
        for (int i = 0; i < 11; ++i) red[i][wv] = v[i];
    }
    __syncthreads();

    const int t = threadIdx.x;
    if (t < 112) {                            // 16 j x 7 comps
        const int j = t / 7, c = t % 7;
        const float s = jacc[j][c][0] + jacc[j][c][1] + jacc[j][c][2] + jacc[j][c][3];
        atomicAdd(&ws[38 + (b * 16 + j) * 7 + c], s);
    } else if (t >= 128 && t < 139) {
        const int i = t - 128;
        const float s = red[i][0] + red[i][1] + red[i][2] + red[i][3];
        const int g = (i < 2) ? i : (2 + b * 9 + (i - 2));
        atomicAdd(&ws[g], s);
    }
}

// ---- finalize ------------------------------------------------------------
__global__ __launch_bounds__(64) void mvpm_fin(const float* __restrict__ ws,
                                               const float* __restrict__ tp,
                                               float* __restrict__ o) {
    const int t = threadIdx.x;      // (b, j)
    const int base = 38 + t * 7;

    float S = ws[base] + 1e-5f;
    float ln = 0.0f, rn = 0.0f;
#pragma unroll
    for (int c = 0; c < 3; ++c) {
        float pl = ws[base + 1 + c] / S;
        float tl = 1.0f / (1.0f + expf(-tp[t * 6 + c]));
        ln += (pl - tl) * (pl - tl);
        float pr = ws[base + 4 + c] / S;
        float tr = 1.0f / (1.0f + expf(-tp[t * 6 + 3 + c]));
        rn += (pr - tr) * (pr - tr);
    }
    ln = sqrtf(ln);
    rn = sqrtf(rn);
    float lsum = wred(ln);
    float rsum = wred(rn);

    if (t == 0) {
        float nocs = 0.0f, locm = 0.0f, rotm = 0.0f;
        for (int bb = 0; bb < 4; ++bb) {
            int ba = 2 + bb * 9;
            nocs += (ws[ba + 1] > 0.5f) ? ws[ba + 0] / ws[ba + 1] : ws[ba + 2] * (1.0f / HW);
            locm += (ws[ba + 4] > 0.5f) ? ws[ba + 3] / ws[ba + 4] : ws[ba + 5] * (1.0f / HW);
            rotm += (ws[ba + 7] > 0.5f) ? ws[ba + 6] / ws[ba + 7] : ws[ba + 8] * (1.0f / HW);
        }
        o[0] = nocs * 0.25f;                  // nocs_loss
        o[1] = -ws[0] / (4.0f * HW);          // mask_loss
        o[2] = lsum * (1.0f / 64.0f);         // loc_loss
        o[3] = locm * 0.25f;                  // loc_map_loss
        o[4] = rsum * (1.0f / 64.0f);         // rot_loss
        o[5] = rotm * 0.25f;                  // rot_map_loss
        o[6] = ws[1] / (4.0f * HW);           // skin_loss
    }
}

extern "C" void kernel_launch(void* const* d_in, const int* in_sizes, int n_in,
                              void* d_out, int out_size, void* d_ws, size_t ws_size,
                              hipStream_t stream) {
    const float* outp = (const float*)d_in[0];   // (4,134,256,256)
    const float* tarp = (const float*)d_in[1];   // (4,101,256,256)
    const float* tpos = (const float*)d_in[2];   // (4,16,6)
    float* o  = (float*)d_out;                   // 7 floats
    float* ws = (float*)d_ws;

    hipMemsetAsync(d_ws, 0, 486 * sizeof(float), stream);
    dim3 g(HW / 512, 4);                         // 512 blocks, 2 px/thread
    mvpm_fused<<<g, 256, 0, stream>>>(outp, tarp, ws);
    mvpm_fin<<<1, 64, 0, stream>>>(ws, tpos, o);
}

// Round 5
// 279.290 us; speedup vs baseline: 1.3584x; 1.3584x over previous
//
#include <hip/hip_runtime.h>
#include <math.h>

#define HW 65536
#define BN 16
#define C4 (HW / 4)

// ws layout (floats):
//   ws[0] : mask-loss sum,  ws[1] : skin-loss sum
//   per-b block of 9 at ws[2 + b*9]:
//     +0..2 : nocs msum,cnt,dsum  +3..5 : locmap  +6..8 : rotmap
//   per-(b,j) block of 7 at ws[38 + (b*16+j)*7]: S, Nloc0..2, Nrot0..2
// total = 38 + 64*7 = 486 floats

__device__ __forceinline__ float fsig(float x) {
    return __builtin_amdgcn_rcpf(1.0f + __expf(-x));
}
__device__ __forceinline__ float sq(float x) { return x * x; }

__device__ __forceinline__ float wred(float v) {
#pragma unroll
    for (int off = 32; off; off >>= 1) v += __shfl_xor(v, off, 64);
    return v;
}
__device__ __forceinline__ float4 fsig4(float4 a) {
    return make_float4(fsig(a.x), fsig(a.y), fsig(a.z), fsig(a.w));
}

// ---- Fused kernel: float4 loads (1 KB/wave-instr), 4 px/thread -----------
// grid (64, 4) = 256 blocks x 256 thr -> 1 block/CU, 4 waves/CU
__global__ __launch_bounds__(256) void mvpm_fused(const float* __restrict__ outp,
                                                  const float* __restrict__ tarp,
                                                  float* __restrict__ ws) {
    const int b = blockIdx.y;
    const int idx = blockIdx.x * 256 + threadIdx.x;     // float4 index
    const float4* ob = (const float4*)(outp + (size_t)b * 134 * HW) + idx;
    const float4* tb = (const float4*)(tarp + (size_t)b * 101 * HW) + idx;
    const int lane = threadIdx.x & 63;
    const int wv = threadIdx.x >> 6;

    __shared__ float jacc[BN][7][4];    // per-j, per-component, per-wave
    __shared__ float red[11][4];

    // -- mask, mask-logit, nocs (8 x float4) --
    const float4 fm = tb[3 * C4];
    const float4 ml = ob[3 * C4];
    const float4 a0 = ob[0], a1 = ob[C4], a2 = ob[2 * C4];
    const float4 b0 = tb[0], b1 = tb[C4], b2 = tb[2 * C4];

    float bce = 0.0f;
#define BCE1(c) bce += fm.c * fminf(ml.c, 0.0f) + (1.0f - fm.c) * fminf(-ml.c, 0.0f) \
                       - __logf(1.0f + __expf(-fabsf(ml.c)));
    BCE1(x) BCE1(y) BCE1(z) BCE1(w)
#undef BCE1

    float4 dn;
    dn.x = sqrtf(sq(a0.x - b0.x) + sq(a1.x - b1.x) + sq(a2.x - b2.x));
    dn.y = sqrtf(sq(a0.y - b0.y) + sq(a1.y - b1.y) + sq(a2.y - b2.y));
    dn.z = sqrtf(sq(a0.z - b0.z) + sq(a1.z - b1.z) + sq(a2.z - b2.z));
    dn.w = sqrtf(sq(a0.w - b0.w) + sq(a1.w - b1.w) + sq(a2.w - b2.w));
    const float4 mm = make_float4(fm.x * fm.x, fm.y * fm.y, fm.z * fm.z, fm.w * fm.w);

    // -- skin CE: 18-channel float4 batch --
    float4 xx[18];
#pragma unroll
    for (int k = 0; k < 18; ++k) xx[k] = ob[(100 + k) * C4];
    const float4 labf = tb[100 * C4];
    float skin = 0.0f;
#define SKIN1(c) {                                                             \
        float mx = xx[0].c;                                                    \
        _Pragma("unroll")                                                      \
        for (int k = 1; k < 18; ++k) mx = fmaxf(mx, xx[k].c);                  \
        float se = 0.0f;                                                       \
        _Pragma("unroll")                                                      \
        for (int k = 0; k < 18; ++k) se += __expf(xx[k].c - mx);               \
        int lab = (int)labf.c; lab = lab < 0 ? 0 : (lab > 17 ? 17 : lab);      \
        float xl = xx[0].c;                                                    \
        _Pragma("unroll")                                                      \
        for (int k = 1; k < 18; ++k) xl = (lab == k) ? xx[k].c : xl;           \
        skin += mx + __logf(se) - xl; }
    SKIN1(x) SKIN1(y) SKIN1(z) SKIN1(w)
#undef SKIN1

    // -- joint loop: 13 float4 loads / j, single-buffered, inline reduce --
    float4 dsl = make_float4(0.f, 0.f, 0.f, 0.f);
    float4 dsr = make_float4(0.f, 0.f, 0.f, 0.f);
#pragma unroll 2
    for (int j = 0; j < BN; ++j) {
        const int cl = (4 + 3 * j) * C4, cr = (52 + 3 * j) * C4;
        const float4 o0 = ob[cl], o1 = ob[cl + C4], o2 = ob[cl + 2 * C4];
        const float4 t0 = tb[cl], t1 = tb[cl + C4], t2 = tb[cl + 2 * C4];
        const float4 p0 = ob[cr], p1 = ob[cr + C4], p2 = ob[cr + 2 * C4];
        const float4 q0 = tb[cr], q1 = tb[cr + C4], q2 = tb[cr + 2 * C4];
        const float4 sc = ob[(118 + j) * C4];

        const float4 so0 = fsig4(o0), so1 = fsig4(o1), so2 = fsig4(o2);
        const float4 sp0 = fsig4(p0), sp1 = fsig4(p1), sp2 = fsig4(p2);
        const float4 st0 = fsig4(t0), st1 = fsig4(t1), st2 = fsig4(t2);
        const float4 uq0 = fsig4(q0), uq1 = fsig4(q1), uq2 = fsig4(q2);
        const float4 ss = fsig4(sc);

#define ACCJ(c) dsl.c += sq(so0.c - st0.c) + sq(so1.c - st1.c) + sq(so2.c - st2.c); \
                dsr.c += sq(sp0.c - uq0.c) + sq(sp1.c - uq1.c) + sq(sp2.c - uq2.c);
        ACCJ(x) ACCJ(y) ACCJ(z) ACCJ(w)
#undef ACCJ

        const float4 w4 = make_float4(ss.x * mm.x, ss.y * mm.y, ss.z * mm.z, ss.w * mm.w);
        float u[7];
        u[0] = ss.x * fm.x + ss.y * fm.y + ss.z * fm.z + ss.w * fm.w;
#define DOT4(v4) (v4.x * w4.x + v4.y * w4.y + v4.z * w4.z + v4.w * w4.w)
        u[1] = DOT4(so0); u[2] = DOT4(so1); u[3] = DOT4(so2);
        u[4] = DOT4(sp0); u[5] = DOT4(sp1); u[6] = DOT4(sp2);
#undef DOT4

#pragma unroll
        for (int off = 32; off; off >>= 1) {
#pragma unroll
            for (int i = 0; i < 7; ++i) u[i] += __shfl_xor(u[i], off, 64);
        }
        if (lane == 0) {
#pragma unroll
            for (int i = 0; i < 7; ++i) jacc[j][i][wv] = u[i];
        }
    }

    float4 dnl, dnr;
    dnl.x = sqrtf(dsl.x); dnl.y = sqrtf(dsl.y); dnl.z = sqrtf(dsl.z); dnl.w = sqrtf(dsl.w);
    dnr.x = sqrtf(dsr.x); dnr.y = sqrtf(dsr.y); dnr.z = sqrtf(dsr.z); dnr.w = sqrtf(dsr.w);

    // -- 11 pixel-loss wave reductions, all 4 pixels pre-summed --
    float v[11];
    v[0] = bce;
    v[1] = skin;
#pragma unroll
    for (int i = 2; i < 11; ++i) v[i] = 0.0f;
#define PIX1(c) {                                                              \
        const bool sel = fm.c > 0.7f;                                          \
        v[2]  += sel ? dn.c : 0.0f;                                            \
        v[3]  += (sel && dn.c != 0.0f) ? 1.0f : 0.0f;                          \
        v[4]  += dn.c;                                                         \
        v[5]  += sel ? dnl.c : 0.0f;                                           \
        v[6]  += (sel && dnl.c != 0.0f) ? 1.0f : 0.0f;                         \
        v[7]  += dnl.c;                                                        \
        v[8]  += sel ? dnr.c : 0.0f;                                           \
        v[9]  += (sel && dnr.c != 0.0f) ? 1.0f : 0.0f;                         \
        v[10] += dnr.c; }
    PIX1(x) PIX1(y) PIX1(z) PIX1(w)
#undef PIX1

#pragma unroll
    for (int off = 32; off; off >>= 1) {
#pragma unroll
        for (int i = 0; i < 11; ++i) v[i] += __shfl_xor(v[i], off, 64);
    }
    if (lane == 0) {
#pragma unroll
        for (int i = 0; i < 11; ++i) red[i][wv] = v[i];
    }
    __syncthreads();

    const int t = threadIdx.x;
    if (t < 112) {                            // 16 j x 7 comps
        const int j = t / 7, c = t % 7;
        const float s = jacc[j][c][0] + jacc[j][c][1] + jacc[j][c][2] + jacc[j][c][3];
        atomicAdd(&ws[38 + (b * 16 + j) * 7 + c], s);
    } else if (t >= 128 && t < 139) {
        const int i = t - 128;
        const float s = red[i][0] + red[i][1] + red[i][2] + red[i][3];
        const int g = (i < 2) ? i : (2 + b * 9 + (i - 2));
        atomicAdd(&ws[g], s);
    }
}

// ---- finalize ------------------------------------------------------------
__global__ __launch_bounds__(64) void mvpm_fin(const float* __restrict__ ws,
                                               const float* __restrict__ tp,
                                               float* __restrict__ o) {
    const int t = threadIdx.x;      // (b, j)
    const int base = 38 + t * 7;

    float S = ws[base] + 1e-5f;
    float ln = 0.0f, rn = 0.0f;
#pragma unroll
    for (int c = 0; c < 3; ++c) {
        float pl = ws[base + 1 + c] / S;
        float tl = 1.0f / (1.0f + expf(-tp[t * 6 + c]));
        ln += (pl - tl) * (pl - tl);
        float pr = ws[base + 4 + c] / S;
        float tr = 1.0f / (1.0f + expf(-tp[t * 6 + 3 + c]));
        rn += (pr - tr) * (pr - tr);
    }
    ln = sqrtf(ln);
    rn = sqrtf(rn);
    float lsum = wred(ln);
    float rsum = wred(rn);

    if (t == 0) {
        float nocs = 0.0f, locm = 0.0f, rotm = 0.0f;
        for (int bb = 0; bb < 4; ++bb) {
            int ba = 2 + bb * 9;
            nocs += (ws[ba + 1] > 0.5f) ? ws[ba + 0] / ws[ba + 1] : ws[ba + 2] * (1.0f / HW);
            locm += (ws[ba + 4] > 0.5f) ? ws[ba + 3] / ws[ba + 4] : ws[ba + 5] * (1.0f / HW);
            rotm += (ws[ba + 7] > 0.5f) ? ws[ba + 6] / ws[ba + 7] : ws[ba + 8] * (1.0f / HW);
        }
        o[0] = nocs * 0.25f;                  // nocs_loss
        o[1] = -ws[0] / (4.0f * HW);          // mask_loss
        o[2] = lsum * (1.0f / 64.0f);         // loc_loss
        o[3] = locm * 0.25f;                  // loc_map_loss
        o[4] = rsum * (1.0f / 64.0f);         // rot_loss
        o[5] = rotm * 0.25f;                  // rot_map_loss
        o[6] = ws[1] / (4.0f * HW);           // skin_loss
    }
}

extern "C" void kernel_launch(void* const* d_in, const int* in_sizes, int n_in,
                              void* d_out, int out_size, void* d_ws, size_t ws_size,
                              hipStream_t stream) {
    const float* outp = (const float*)d_in[0];   // (4,134,256,256)
    const float* tarp = (const float*)d_in[1];   // (4,101,256,256)
    const float* tpos = (const float*)d_in[2];   // (4,16,6)
    float* o  = (float*)d_out;                   // 7 floats
    float* ws = (float*)d_ws;

    hipMemsetAsync(d_ws, 0, 486 * sizeof(float), stream);
    dim3 g(HW / 1024, 4);                        // 256 blocks, 4 px/thread
    mvpm_fused<<<g, 256, 0, stream>>>(outp, tarp, ws);
    mvpm_fin<<<1, 64, 0, stream>>>(ws, tpos, o);
}